// Round 1
// baseline (1104.578 us; speedup 1.0000x reference)
//
#include <hip/hip_runtime.h>

#define C_DIM 8
#define LRES 128
#define HRES 1024

static const int LVOX = LRES * LRES * LRES;   // 2,097,152 voxels
static const int PPIX = HRES * HRES;          // 1,048,576 pixels per plane

// Replicates reference _to_idx exactly: p=(c+1)*0.5*(size-1); i0=floor(p);
// w=p-floor(p); i0=clip(int(i0),0,size-1); i1=clip(i0+1,0,size-1).
__device__ __forceinline__ void to_idx(float c, int size, int& i0, int& i1, float& w) {
    float p = (c + 1.0f) * 0.5f * (float)(size - 1);
    float f = floorf(p);
    w = p - f;
    int i = (int)f;
    i0 = min(max(i, 0), size - 1);
    i1 = min(i0 + 1, size - 1);
}

// acc += w * base[0..7]  (channels-last, 32B contiguous)
__device__ __forceinline__ void fma8(float4& a0, float4& a1,
                                     const float* __restrict__ base, float w) {
    const float4* p = (const float4*)base;
    float4 u = p[0];
    float4 v = p[1];
    a0.x = fmaf(u.x, w, a0.x); a0.y = fmaf(u.y, w, a0.y);
    a0.z = fmaf(u.z, w, a0.z); a0.w = fmaf(u.w, w, a0.w);
    a1.x = fmaf(v.x, w, a1.x); a1.y = fmaf(v.y, w, a1.y);
    a1.z = fmaf(v.z, w, a1.z); a1.w = fmaf(v.w, w, a1.w);
}

// [C, V] -> [V, C] with C=8. Reads coalesced per channel, writes 32B/thread.
__global__ __launch_bounds__(256) void transpose_cl(const float* __restrict__ src,
                                                    float* __restrict__ dst, int V) {
    int v = blockIdx.x * blockDim.x + threadIdx.x;
    if (v >= V) return;
    float4 a, b;
    a.x = src[(size_t)0 * V + v];
    a.y = src[(size_t)1 * V + v];
    a.z = src[(size_t)2 * V + v];
    a.w = src[(size_t)3 * V + v];
    b.x = src[(size_t)4 * V + v];
    b.y = src[(size_t)5 * V + v];
    b.z = src[(size_t)6 * V + v];
    b.w = src[(size_t)7 * V + v];
    float4* d = (float4*)(dst + (size_t)v * 8);
    d[0] = a;
    d[1] = b;
}

// Fast path: channels-last gathers.
__global__ __launch_bounds__(256) void sample_cl(
    const float* __restrict__ xyz, const int* __restrict__ boundp,
    const float* __restrict__ gcl, const float* __restrict__ pcl,
    float* __restrict__ out, int N) {
    int n = blockIdx.x * blockDim.x + threadIdx.x;
    if (n >= N) return;
    float invb = 1.0f / (float)boundp[0];
    float x = xyz[(size_t)3 * n + 0] * invb;
    float y = xyz[(size_t)3 * n + 1] * invb;
    float z = xyz[(size_t)3 * n + 2] * invb;

    float4 a0 = make_float4(0.f, 0.f, 0.f, 0.f);
    float4 a1 = make_float4(0.f, 0.f, 0.f, 0.f);

    // ---- trilinear from gcl [D,H,W,C]  (x->W, y->H, z->D) ----
    {
        int x0, x1, y0, y1, z0, z1;
        float wx, wy, wz;
        to_idx(x, LRES, x0, x1, wx);
        to_idx(y, LRES, y0, y1, wy);
        to_idx(z, LRES, z0, z1, wz);
        float ux = 1.f - wx, uy = 1.f - wy, uz = 1.f - wz;
        const float* b00 = gcl + ((size_t)z0 * LRES + y0) * LRES * 8;
        const float* b01 = gcl + ((size_t)z0 * LRES + y1) * LRES * 8;
        const float* b10 = gcl + ((size_t)z1 * LRES + y0) * LRES * 8;
        const float* b11 = gcl + ((size_t)z1 * LRES + y1) * LRES * 8;
        fma8(a0, a1, b00 + (size_t)x0 * 8, uz * uy * ux);
        fma8(a0, a1, b00 + (size_t)x1 * 8, uz * uy * wx);
        fma8(a0, a1, b01 + (size_t)x0 * 8, uz * wy * ux);
        fma8(a0, a1, b01 + (size_t)x1 * 8, uz * wy * wx);
        fma8(a0, a1, b10 + (size_t)x0 * 8, wz * uy * ux);
        fma8(a0, a1, b10 + (size_t)x1 * 8, wz * uy * wx);
        fma8(a0, a1, b11 + (size_t)x0 * 8, wz * wy * ux);
        fma8(a0, a1, b11 + (size_t)x1 * 8, wz * wy * wx);
    }

    // ---- bilinear planes from pcl [3][H,W,C] ----
    // plane 0: W<-x, H<-y ; plane 1: W<-y, H<-z ; plane 2: W<-z, H<-x
    {
        const float cw[3] = {x, y, z};
        const float ch[3] = {y, z, x};
#pragma unroll
        for (int p = 0; p < 3; ++p) {
            int w0, w1, h0, h1;
            float ww, wh;
            to_idx(cw[p], HRES, w0, w1, ww);
            to_idx(ch[p], HRES, h0, h1, wh);
            float uw = 1.f - ww, uh = 1.f - wh;
            const float* base = pcl + (size_t)p * PPIX * 8;
            const float* r0 = base + (size_t)h0 * HRES * 8;
            const float* r1 = base + (size_t)h1 * HRES * 8;
            fma8(a0, a1, r0 + (size_t)w0 * 8, uh * uw);
            fma8(a0, a1, r0 + (size_t)w1 * 8, uh * ww);
            fma8(a0, a1, r1 + (size_t)w0 * 8, wh * uw);
            fma8(a0, a1, r1 + (size_t)w1 * 8, wh * ww);
        }
    }

    float4* o = (float4*)(out + (size_t)n * 8);
    o[0] = a0;
    o[1] = a1;
}

// Fallback: channel-first gathers directly on inputs (used if ws too small).
__global__ __launch_bounds__(256) void sample_cf(
    const float* __restrict__ xyz, const int* __restrict__ boundp,
    const float* __restrict__ Lg, const float* __restrict__ Hp,
    float* __restrict__ out, int N) {
    int n = blockIdx.x * blockDim.x + threadIdx.x;
    if (n >= N) return;
    float invb = 1.0f / (float)boundp[0];
    float x = xyz[(size_t)3 * n + 0] * invb;
    float y = xyz[(size_t)3 * n + 1] * invb;
    float z = xyz[(size_t)3 * n + 2] * invb;

    float acc[8];
#pragma unroll
    for (int c = 0; c < 8; ++c) acc[c] = 0.f;

    // trilinear
    {
        int x0, x1, y0, y1, z0, z1;
        float wx, wy, wz;
        to_idx(x, LRES, x0, x1, wx);
        to_idx(y, LRES, y0, y1, wy);
        to_idx(z, LRES, z0, z1, wz);
        float ux = 1.f - wx, uy = 1.f - wy, uz = 1.f - wz;
        size_t i8[8];
        i8[0] = ((size_t)z0 * LRES + y0) * LRES + x0;
        i8[1] = ((size_t)z0 * LRES + y0) * LRES + x1;
        i8[2] = ((size_t)z0 * LRES + y1) * LRES + x0;
        i8[3] = ((size_t)z0 * LRES + y1) * LRES + x1;
        i8[4] = ((size_t)z1 * LRES + y0) * LRES + x0;
        i8[5] = ((size_t)z1 * LRES + y0) * LRES + x1;
        i8[6] = ((size_t)z1 * LRES + y1) * LRES + x0;
        i8[7] = ((size_t)z1 * LRES + y1) * LRES + x1;
        float w8[8] = {uz * uy * ux, uz * uy * wx, uz * wy * ux, uz * wy * wx,
                       wz * uy * ux, wz * uy * wx, wz * wy * ux, wz * wy * wx};
#pragma unroll
        for (int c = 0; c < 8; ++c) {
            const float* g = Lg + (size_t)c * LVOX;
            float s = 0.f;
#pragma unroll
            for (int k = 0; k < 8; ++k) s = fmaf(g[i8[k]], w8[k], s);
            acc[c] += s;
        }
    }
    // planes
    {
        const float cw[3] = {x, y, z};
        const float ch[3] = {y, z, x};
        for (int p = 0; p < 3; ++p) {
            int w0, w1, h0, h1;
            float ww, wh;
            to_idx(cw[p], HRES, w0, w1, ww);
            to_idx(ch[p], HRES, h0, h1, wh);
            float uw = 1.f - ww, uh = 1.f - wh;
            size_t i4[4];
            i4[0] = (size_t)h0 * HRES + w0;
            i4[1] = (size_t)h0 * HRES + w1;
            i4[2] = (size_t)h1 * HRES + w0;
            i4[3] = (size_t)h1 * HRES + w1;
            float w4[4] = {uh * uw, uh * ww, wh * uw, wh * ww};
            const float* pb = Hp + (size_t)p * 8 * PPIX;
#pragma unroll
            for (int c = 0; c < 8; ++c) {
                const float* g = pb + (size_t)c * PPIX;
                float s = 0.f;
#pragma unroll
                for (int k = 0; k < 4; ++k) s = fmaf(g[i4[k]], w4[k], s);
                acc[c] += s;
            }
        }
    }
#pragma unroll
    for (int c = 0; c < 8; ++c) out[(size_t)n * 8 + c] = acc[c];
}

extern "C" void kernel_launch(void* const* d_in, const int* in_sizes, int n_in,
                              void* d_out, int out_size, void* d_ws, size_t ws_size,
                              hipStream_t stream) {
    const float* xyz = (const float*)d_in[0];
    const int* bound = (const int*)d_in[1];
    const float* Lg = (const float*)d_in[2];   // [8, 128,128,128]
    const float* Hp = (const float*)d_in[3];   // [3, 8, 1024,1024]
    float* out = (float*)d_out;
    int N = in_sizes[0] / 3;

    const size_t gcl_elems = (size_t)LVOX * 8;       // 16,777,216
    const size_t pcl_elems = (size_t)3 * PPIX * 8;   // 25,165,824
    const size_t need = (gcl_elems + pcl_elems) * sizeof(float);  // 160 MiB

    if (ws_size >= need) {
        float* gcl = (float*)d_ws;
        float* pcl = gcl + gcl_elems;
        transpose_cl<<<(LVOX + 255) / 256, 256, 0, stream>>>(Lg, gcl, LVOX);
        for (int p = 0; p < 3; ++p) {
            transpose_cl<<<(PPIX + 255) / 256, 256, 0, stream>>>(
                Hp + (size_t)p * 8 * PPIX, pcl + (size_t)p * PPIX * 8, PPIX);
        }
        sample_cl<<<(N + 255) / 256, 256, 0, stream>>>(xyz, bound, gcl, pcl, out, N);
    } else {
        sample_cf<<<(N + 255) / 256, 256, 0, stream>>>(xyz, bound, Lg, Hp, out, N);
    }
}

// Round 2
// 560.675 us; speedup vs baseline: 1.9701x; 1.9701x over previous
//
#include <hip/hip_runtime.h>

#define LRES 128
#define HRES 1024
#define CELLS_BITS 6                   // 64^3 Morton cells
#define NCELLS (1 << (3 * CELLS_BITS)) // 262144

static const int LVOX = LRES * LRES * LRES; // 2,097,152
static const int PPIX = HRES * HRES;        // 1,048,576

// ---------- helpers ----------

// Replicates reference _to_idx exactly.
__device__ __forceinline__ void to_idx(float c, int size, int& i0, int& i1, float& w) {
    float p = (c + 1.0f) * 0.5f * (float)(size - 1);
    float f = floorf(p);
    w = p - f;
    int i = (int)f;
    i0 = min(max(i, 0), size - 1);
    i1 = min(i0 + 1, size - 1);
}

// float -> bf16 (RNE)
__device__ __forceinline__ unsigned f2bf(float f) {
    unsigned u = __float_as_uint(f);
    return (u + 0x7FFFu + ((u >> 16) & 1u)) >> 16;
}
__device__ __forceinline__ float bflo(unsigned u) { return __uint_as_float(u << 16); }
__device__ __forceinline__ float bfhi(unsigned u) { return __uint_as_float(u & 0xFFFF0000u); }

// acc += w * corner[0..7]   (corner = 8 bf16 packed in one uint4)
__device__ __forceinline__ void fma8b(float4& a0, float4& a1,
                                      const uint4* __restrict__ p, float w) {
    uint4 q = *p;
    a0.x = fmaf(bflo(q.x), w, a0.x);
    a0.y = fmaf(bfhi(q.x), w, a0.y);
    a0.z = fmaf(bflo(q.y), w, a0.z);
    a0.w = fmaf(bfhi(q.y), w, a0.w);
    a1.x = fmaf(bflo(q.z), w, a1.x);
    a1.y = fmaf(bfhi(q.z), w, a1.y);
    a1.z = fmaf(bflo(q.w), w, a1.z);
    a1.w = fmaf(bfhi(q.w), w, a1.w);
}

__device__ __forceinline__ unsigned spread3(unsigned x) {
    x &= 0x3FFu;
    x = (x | (x << 16)) & 0x030000FFu;
    x = (x | (x << 8)) & 0x0300F00Fu;
    x = (x | (x << 4)) & 0x030C30C3u;
    x = (x | (x << 2)) & 0x09249249u;
    return x;
}
__device__ __forceinline__ unsigned cell_of(float x, float y, float z) {
    int cx = min(max((int)(x * 64.f), 0), 63);
    int cy = min(max((int)(y * 64.f), 0), 63);
    int cz = min(max((int)(z * 64.f), 0), 63);
    return spread3(cx) | (spread3(cy) << 1) | (spread3(cz) << 2);
}

// ---------- table transpose to channels-last bf16 ----------
// src [8, V] fp32 -> dst [V] of uint4 (8 bf16)
__global__ __launch_bounds__(256) void transpose_bf(const float* __restrict__ src,
                                                    uint4* __restrict__ dst, int V) {
    int v = blockIdx.x * blockDim.x + threadIdx.x;
    if (v >= V) return;
    unsigned h[8];
#pragma unroll
    for (int c = 0; c < 8; ++c) h[c] = f2bf(src[(size_t)c * V + v]);
    uint4 o;
    o.x = h[0] | (h[1] << 16);
    o.y = h[2] | (h[3] << 16);
    o.z = h[4] | (h[5] << 16);
    o.w = h[6] | (h[7] << 16);
    dst[v] = o;
}

// ---------- counting sort ----------
__global__ __launch_bounds__(256) void hist_k(const float* __restrict__ xyz,
                                              const int* __restrict__ boundp,
                                              unsigned* __restrict__ hist, int N) {
    int n = blockIdx.x * blockDim.x + threadIdx.x;
    if (n >= N) return;
    float invb = 1.0f / (float)boundp[0];
    float x = xyz[(size_t)3 * n + 0] * invb;
    float y = xyz[(size_t)3 * n + 1] * invb;
    float z = xyz[(size_t)3 * n + 2] * invb;
    atomicAdd(&hist[cell_of(x, y, z)], 1u);
}

__global__ __launch_bounds__(256) void scan1_k(unsigned* __restrict__ h,
                                               unsigned* __restrict__ bsum) {
    __shared__ unsigned s[256];
    int tid = threadIdx.x;
    int i = blockIdx.x * 256 + tid;
    unsigned v = h[i];
    s[tid] = v;
    __syncthreads();
    for (int o = 1; o < 256; o <<= 1) {
        unsigned t = (tid >= o) ? s[tid - o] : 0u;
        __syncthreads();
        s[tid] += t;
        __syncthreads();
    }
    h[i] = s[tid] - v; // exclusive
    if (tid == 255) bsum[blockIdx.x] = s[tid];
}

__global__ __launch_bounds__(1024) void scan2_k(unsigned* __restrict__ bsum, int n) {
    __shared__ unsigned s[1024];
    int tid = threadIdx.x;
    unsigned v = (tid < n) ? bsum[tid] : 0u;
    s[tid] = v;
    __syncthreads();
    for (int o = 1; o < 1024; o <<= 1) {
        unsigned t = (tid >= o) ? s[tid - o] : 0u;
        __syncthreads();
        s[tid] += t;
        __syncthreads();
    }
    if (tid < n) bsum[tid] = s[tid] - v; // exclusive
}

__global__ __launch_bounds__(256) void scan3_k(unsigned* __restrict__ h,
                                               const unsigned* __restrict__ bsum) {
    int i = blockIdx.x * 256 + threadIdx.x;
    h[i] += bsum[blockIdx.x];
}

__global__ __launch_bounds__(256) void scatter_k(const float* __restrict__ xyz,
                                                 const int* __restrict__ boundp,
                                                 unsigned* __restrict__ offs,
                                                 float4* __restrict__ sorted, int N) {
    int n = blockIdx.x * blockDim.x + threadIdx.x;
    if (n >= N) return;
    float invb = 1.0f / (float)boundp[0];
    float x = xyz[(size_t)3 * n + 0] * invb;
    float y = xyz[(size_t)3 * n + 1] * invb;
    float z = xyz[(size_t)3 * n + 2] * invb;
    unsigned c = cell_of(x, y, z);
    unsigned d = atomicAdd(&offs[c], 1u);
    sorted[d] = make_float4(x, y, z, __int_as_float(n));
}

// ---------- main sampler (sorted order, bf16 channels-last tables) ----------
__global__ __launch_bounds__(256) void sample_srt(const float4* __restrict__ sorted,
                                                  const uint4* __restrict__ gclb,
                                                  const uint4* __restrict__ pclb,
                                                  float* __restrict__ out, int N) {
    int i = blockIdx.x * blockDim.x + threadIdx.x;
    if (i >= N) return;
    float4 rec = sorted[i];
    float x = rec.x, y = rec.y, z = rec.z;
    int idx = __float_as_int(rec.w);

    float4 a0 = make_float4(0.f, 0.f, 0.f, 0.f);
    float4 a1 = make_float4(0.f, 0.f, 0.f, 0.f);

    // trilinear from gclb [D,H,W] of uint4  (x->W, y->H, z->D)
    {
        int x0, x1, y0, y1, z0, z1;
        float wx, wy, wz;
        to_idx(x, LRES, x0, x1, wx);
        to_idx(y, LRES, y0, y1, wy);
        to_idx(z, LRES, z0, z1, wz);
        float ux = 1.f - wx, uy = 1.f - wy, uz = 1.f - wz;
        const uint4* b00 = gclb + ((size_t)z0 * LRES + y0) * LRES;
        const uint4* b01 = gclb + ((size_t)z0 * LRES + y1) * LRES;
        const uint4* b10 = gclb + ((size_t)z1 * LRES + y0) * LRES;
        const uint4* b11 = gclb + ((size_t)z1 * LRES + y1) * LRES;
        fma8b(a0, a1, b00 + x0, uz * uy * ux);
        fma8b(a0, a1, b00 + x1, uz * uy * wx);
        fma8b(a0, a1, b01 + x0, uz * wy * ux);
        fma8b(a0, a1, b01 + x1, uz * wy * wx);
        fma8b(a0, a1, b10 + x0, wz * uy * ux);
        fma8b(a0, a1, b10 + x1, wz * uy * wx);
        fma8b(a0, a1, b11 + x0, wz * wy * ux);
        fma8b(a0, a1, b11 + x1, wz * wy * wx);
    }
    // bilinear planes: p0 (W<-x,H<-y), p1 (W<-y,H<-z), p2 (W<-z,H<-x)
    {
        const float cw[3] = {x, y, z};
        const float ch[3] = {y, z, x};
#pragma unroll
        for (int p = 0; p < 3; ++p) {
            int w0, w1, h0, h1;
            float ww, wh;
            to_idx(cw[p], HRES, w0, w1, ww);
            to_idx(ch[p], HRES, h0, h1, wh);
            float uw = 1.f - ww, uh = 1.f - wh;
            const uint4* base = pclb + (size_t)p * PPIX;
            const uint4* r0 = base + (size_t)h0 * HRES;
            const uint4* r1 = base + (size_t)h1 * HRES;
            fma8b(a0, a1, r0 + w0, uh * uw);
            fma8b(a0, a1, r0 + w1, uh * ww);
            fma8b(a0, a1, r1 + w0, wh * uw);
            fma8b(a0, a1, r1 + w1, wh * ww);
        }
    }

    float4* o = (float4*)(out + (size_t)idx * 8);
    o[0] = a0;
    o[1] = a1;
}

// ---------- fallback (channel-first fp32 direct, known-correct) ----------
__global__ __launch_bounds__(256) void sample_cf(
    const float* __restrict__ xyz, const int* __restrict__ boundp,
    const float* __restrict__ Lg, const float* __restrict__ Hp,
    float* __restrict__ out, int N) {
    int n = blockIdx.x * blockDim.x + threadIdx.x;
    if (n >= N) return;
    float invb = 1.0f / (float)boundp[0];
    float x = xyz[(size_t)3 * n + 0] * invb;
    float y = xyz[(size_t)3 * n + 1] * invb;
    float z = xyz[(size_t)3 * n + 2] * invb;
    float acc[8];
#pragma unroll
    for (int c = 0; c < 8; ++c) acc[c] = 0.f;
    {
        int x0, x1, y0, y1, z0, z1;
        float wx, wy, wz;
        to_idx(x, LRES, x0, x1, wx);
        to_idx(y, LRES, y0, y1, wy);
        to_idx(z, LRES, z0, z1, wz);
        float ux = 1.f - wx, uy = 1.f - wy, uz = 1.f - wz;
        size_t i8[8];
        i8[0] = ((size_t)z0 * LRES + y0) * LRES + x0;
        i8[1] = ((size_t)z0 * LRES + y0) * LRES + x1;
        i8[2] = ((size_t)z0 * LRES + y1) * LRES + x0;
        i8[3] = ((size_t)z0 * LRES + y1) * LRES + x1;
        i8[4] = ((size_t)z1 * LRES + y0) * LRES + x0;
        i8[5] = ((size_t)z1 * LRES + y0) * LRES + x1;
        i8[6] = ((size_t)z1 * LRES + y1) * LRES + x0;
        i8[7] = ((size_t)z1 * LRES + y1) * LRES + x1;
        float w8[8] = {uz * uy * ux, uz * uy * wx, uz * wy * ux, uz * wy * wx,
                       wz * uy * ux, wz * uy * wx, wz * wy * ux, wz * wy * wx};
#pragma unroll
        for (int c = 0; c < 8; ++c) {
            const float* g = Lg + (size_t)c * LVOX;
            float s = 0.f;
#pragma unroll
            for (int k = 0; k < 8; ++k) s = fmaf(g[i8[k]], w8[k], s);
            acc[c] += s;
        }
    }
    {
        const float cw[3] = {x, y, z};
        const float ch[3] = {y, z, x};
        for (int p = 0; p < 3; ++p) {
            int w0, w1, h0, h1;
            float ww, wh;
            to_idx(cw[p], HRES, w0, w1, ww);
            to_idx(ch[p], HRES, h0, h1, wh);
            float uw = 1.f - ww, uh = 1.f - wh;
            size_t i4[4] = {(size_t)h0 * HRES + w0, (size_t)h0 * HRES + w1,
                            (size_t)h1 * HRES + w0, (size_t)h1 * HRES + w1};
            float w4[4] = {uh * uw, uh * ww, wh * uw, wh * ww};
            const float* pb = Hp + (size_t)p * 8 * PPIX;
#pragma unroll
            for (int c = 0; c < 8; ++c) {
                const float* g = pb + (size_t)c * PPIX;
                float s = 0.f;
#pragma unroll
                for (int k = 0; k < 4; ++k) s = fmaf(g[i4[k]], w4[k], s);
                acc[c] += s;
            }
        }
    }
#pragma unroll
    for (int c = 0; c < 8; ++c) out[(size_t)n * 8 + c] = acc[c];
}

extern "C" void kernel_launch(void* const* d_in, const int* in_sizes, int n_in,
                              void* d_out, int out_size, void* d_ws, size_t ws_size,
                              hipStream_t stream) {
    const float* xyz = (const float*)d_in[0];
    const int* bound = (const int*)d_in[1];
    const float* Lg = (const float*)d_in[2]; // [8,128,128,128]
    const float* Hp = (const float*)d_in[3]; // [3,8,1024,1024]
    float* out = (float*)d_out;
    int N = in_sizes[0] / 3;

    // workspace layout (bytes)
    size_t off = 0;
    size_t gclb_b = (size_t)LVOX * 16;      // 33,554,432
    size_t pclb_b = (size_t)3 * PPIX * 16;  // 50,331,648
    size_t sort_b = (size_t)N * 16;         // 32,000,000
    size_t hist_b = (size_t)NCELLS * 4;     // 1,048,576
    size_t bsum_b = (size_t)(NCELLS / 256) * 4; // 4096
    size_t need = gclb_b + pclb_b + sort_b + hist_b + bsum_b;

    if (ws_size >= need) {
        char* w = (char*)d_ws;
        uint4* gclb = (uint4*)(w + (off));           off += gclb_b;
        uint4* pclb = (uint4*)(w + off);             off += pclb_b;
        float4* sorted = (float4*)(w + off);         off += sort_b;
        unsigned* hist = (unsigned*)(w + off);       off += hist_b;
        unsigned* bsum = (unsigned*)(w + off);

        transpose_bf<<<(LVOX + 255) / 256, 256, 0, stream>>>(Lg, gclb, LVOX);
        for (int p = 0; p < 3; ++p) {
            transpose_bf<<<(PPIX + 255) / 256, 256, 0, stream>>>(
                Hp + (size_t)p * 8 * PPIX, pclb + (size_t)p * PPIX, PPIX);
        }
        hipMemsetAsync(hist, 0, hist_b, stream);
        hist_k<<<(N + 255) / 256, 256, 0, stream>>>(xyz, bound, hist, N);
        scan1_k<<<NCELLS / 256, 256, 0, stream>>>(hist, bsum);
        scan2_k<<<1, 1024, 0, stream>>>(bsum, NCELLS / 256);
        scan3_k<<<NCELLS / 256, 256, 0, stream>>>(hist, bsum);
        scatter_k<<<(N + 255) / 256, 256, 0, stream>>>(xyz, bound, hist, sorted, N);
        sample_srt<<<(N + 255) / 256, 256, 0, stream>>>(sorted, gclb, pclb, out, N);
    } else {
        sample_cf<<<(N + 255) / 256, 256, 0, stream>>>(xyz, bound, Lg, Hp, out, N);
    }
}

// Round 3
// 526.248 us; speedup vs baseline: 2.0990x; 1.0654x over previous
//
#include <hip/hip_runtime.h>

#define LRES 128
#define HRES 1024
#define CELLS_BITS 6                   // 64^3 Morton cells
#define NCELLS (1 << (3 * CELLS_BITS)) // 262144
#define SCAT_PASSES 4                  // chunked scatter: 8 MB dest per pass

static const int LVOX = LRES * LRES * LRES; // 2,097,152
static const int PPIX = HRES * HRES;        // 1,048,576

// ---------- helpers ----------

// Replicates reference _to_idx exactly.
__device__ __forceinline__ void to_idx(float c, int size, int& i0, int& i1, float& w) {
    float p = (c + 1.0f) * 0.5f * (float)(size - 1);
    float f = floorf(p);
    w = p - f;
    int i = (int)f;
    i0 = min(max(i, 0), size - 1);
    i1 = min(i0 + 1, size - 1);
}

// float -> bf16 (RNE)
__device__ __forceinline__ unsigned f2bf(float f) {
    unsigned u = __float_as_uint(f);
    return (u + 0x7FFFu + ((u >> 16) & 1u)) >> 16;
}
__device__ __forceinline__ float bflo(unsigned u) { return __uint_as_float(u << 16); }
__device__ __forceinline__ float bfhi(unsigned u) { return __uint_as_float(u & 0xFFFF0000u); }

// acc += w * corner[0..7]   (corner = 8 bf16 packed in one uint4, already loaded)
__device__ __forceinline__ void fma8u(float4& a0, float4& a1, uint4 q, float w) {
    a0.x = fmaf(bflo(q.x), w, a0.x);
    a0.y = fmaf(bfhi(q.x), w, a0.y);
    a0.z = fmaf(bflo(q.y), w, a0.z);
    a0.w = fmaf(bfhi(q.y), w, a0.w);
    a1.x = fmaf(bflo(q.z), w, a1.x);
    a1.y = fmaf(bfhi(q.z), w, a1.y);
    a1.z = fmaf(bflo(q.w), w, a1.z);
    a1.w = fmaf(bfhi(q.w), w, a1.w);
}

__device__ __forceinline__ unsigned spread3(unsigned x) {
    x &= 0x3FFu;
    x = (x | (x << 16)) & 0x030000FFu;
    x = (x | (x << 8)) & 0x0300F00Fu;
    x = (x | (x << 4)) & 0x030C30C3u;
    x = (x | (x << 2)) & 0x09249249u;
    return x;
}
__device__ __forceinline__ unsigned cell_of(float x, float y, float z) {
    int cx = min(max((int)(x * 64.f), 0), 63);
    int cy = min(max((int)(y * 64.f), 0), 63);
    int cz = min(max((int)(z * 64.f), 0), 63);
    return spread3(cx) | (spread3(cy) << 1) | (spread3(cz) << 2);
}

// ---------- table transpose to channels-last bf16 ----------
// src [8, V] fp32 -> dst [V] of uint4 (8 bf16)
__global__ __launch_bounds__(256) void transpose_bf(const float* __restrict__ src,
                                                    uint4* __restrict__ dst, int V) {
    int v = blockIdx.x * blockDim.x + threadIdx.x;
    if (v >= V) return;
    unsigned h[8];
#pragma unroll
    for (int c = 0; c < 8; ++c) h[c] = f2bf(src[(size_t)c * V + v]);
    uint4 o;
    o.x = h[0] | (h[1] << 16);
    o.y = h[2] | (h[3] << 16);
    o.z = h[4] | (h[5] << 16);
    o.w = h[6] | (h[7] << 16);
    dst[v] = o;
}

// ---------- counting sort ----------
__global__ __launch_bounds__(256) void hist_k(const float* __restrict__ xyz,
                                              const int* __restrict__ boundp,
                                              unsigned* __restrict__ hist, int N) {
    int n = blockIdx.x * blockDim.x + threadIdx.x;
    if (n >= N) return;
    float invb = 1.0f / (float)boundp[0];
    float x = xyz[(size_t)3 * n + 0] * invb;
    float y = xyz[(size_t)3 * n + 1] * invb;
    float z = xyz[(size_t)3 * n + 2] * invb;
    atomicAdd(&hist[cell_of(x, y, z)], 1u);
}

// exclusive scan within 256-cell blocks; block totals -> bsum
__global__ __launch_bounds__(256) void scan1_k(unsigned* __restrict__ h,
                                               unsigned* __restrict__ bsum) {
    __shared__ unsigned s[256];
    int tid = threadIdx.x;
    int i = blockIdx.x * 256 + tid;
    unsigned v = h[i];
    s[tid] = v;
    __syncthreads();
    for (int o = 1; o < 256; o <<= 1) {
        unsigned t = (tid >= o) ? s[tid - o] : 0u;
        __syncthreads();
        s[tid] += t;
        __syncthreads();
    }
    h[i] = s[tid] - v; // exclusive within block
    if (tid == 255) bsum[blockIdx.x] = s[tid];
}

// exclusive scan of the 1024 block sums
__global__ __launch_bounds__(1024) void scan2_k(unsigned* __restrict__ bsum, int n) {
    __shared__ unsigned s[1024];
    int tid = threadIdx.x;
    unsigned v = (tid < n) ? bsum[tid] : 0u;
    s[tid] = v;
    __syncthreads();
    for (int o = 1; o < 1024; o <<= 1) {
        unsigned t = (tid >= o) ? s[tid - o] : 0u;
        __syncthreads();
        s[tid] += t;
        __syncthreads();
    }
    if (tid < n) bsum[tid] = s[tid] - v; // exclusive
}

// Scatter pass p: only points whose cell is in chunk p (contiguous ~8MB dest,
// L2-resident so stores coalesce in L2 instead of 64B-line write amplification).
// Final offset = block-local ticket + bsum[c>>8]  (scan3 folded in).
__global__ __launch_bounds__(256) void scatter_k(const float* __restrict__ xyz,
                                                 const int* __restrict__ boundp,
                                                 unsigned* __restrict__ offs,
                                                 const unsigned* __restrict__ bsum,
                                                 float4* __restrict__ sorted, int N,
                                                 int pass) {
    int n = blockIdx.x * blockDim.x + threadIdx.x;
    if (n >= N) return;
    float invb = 1.0f / (float)boundp[0];
    float x = xyz[(size_t)3 * n + 0] * invb;
    float y = xyz[(size_t)3 * n + 1] * invb;
    float z = xyz[(size_t)3 * n + 2] * invb;
    unsigned c = cell_of(x, y, z);
    if ((int)(c / (NCELLS / SCAT_PASSES)) != pass) return;
    unsigned d = atomicAdd(&offs[c], 1u) + bsum[c >> 8];
    sorted[d] = make_float4(x, y, z, __int_as_float(n));
}

// ---------- main sampler (sorted order, bf16 channels-last tables) ----------
__global__ __launch_bounds__(256) void sample_srt(const float4* __restrict__ sorted,
                                                  const uint4* __restrict__ gclb,
                                                  const uint4* __restrict__ pclb,
                                                  float* __restrict__ out, int N) {
    int i = blockIdx.x * blockDim.x + threadIdx.x;
    if (i >= N) return;
    float4 rec = sorted[i];
    float x = rec.x, y = rec.y, z = rec.z;
    int idx = __float_as_int(rec.w);

    float4 a0 = make_float4(0.f, 0.f, 0.f, 0.f);
    float4 a1 = make_float4(0.f, 0.f, 0.f, 0.f);

    // trilinear from gclb [D,H,W] of uint4  (x->W, y->H, z->D)
    {
        int x0, x1, y0, y1, z0, z1;
        float wx, wy, wz;
        to_idx(x, LRES, x0, x1, wx);
        to_idx(y, LRES, y0, y1, wy);
        to_idx(z, LRES, z0, z1, wz);
        float ux = 1.f - wx, uy = 1.f - wy, uz = 1.f - wz;
        const uint4* b00 = gclb + ((size_t)z0 * LRES + y0) * LRES;
        const uint4* b01 = gclb + ((size_t)z0 * LRES + y1) * LRES;
        const uint4* b10 = gclb + ((size_t)z1 * LRES + y0) * LRES;
        const uint4* b11 = gclb + ((size_t)z1 * LRES + y1) * LRES;
        // issue all 8 loads, then FMA (load ILP)
        uint4 q0 = b00[x0], q1 = b00[x1], q2 = b01[x0], q3 = b01[x1];
        uint4 q4 = b10[x0], q5 = b10[x1], q6 = b11[x0], q7 = b11[x1];
        fma8u(a0, a1, q0, uz * uy * ux);
        fma8u(a0, a1, q1, uz * uy * wx);
        fma8u(a0, a1, q2, uz * wy * ux);
        fma8u(a0, a1, q3, uz * wy * wx);
        fma8u(a0, a1, q4, wz * uy * ux);
        fma8u(a0, a1, q5, wz * uy * wx);
        fma8u(a0, a1, q6, wz * wy * ux);
        fma8u(a0, a1, q7, wz * wy * wx);
    }
    // bilinear planes: p0 (W<-x,H<-y), p1 (W<-y,H<-z), p2 (W<-z,H<-x)
    {
        const float cw[3] = {x, y, z};
        const float ch[3] = {y, z, x};
#pragma unroll
        for (int p = 0; p < 3; ++p) {
            int w0, w1, h0, h1;
            float ww, wh;
            to_idx(cw[p], HRES, w0, w1, ww);
            to_idx(ch[p], HRES, h0, h1, wh);
            float uw = 1.f - ww, uh = 1.f - wh;
            const uint4* base = pclb + (size_t)p * PPIX;
            const uint4* r0 = base + (size_t)h0 * HRES;
            const uint4* r1 = base + (size_t)h1 * HRES;
            uint4 q0 = r0[w0], q1 = r0[w1], q2 = r1[w0], q3 = r1[w1];
            fma8u(a0, a1, q0, uh * uw);
            fma8u(a0, a1, q1, uh * ww);
            fma8u(a0, a1, q2, wh * uw);
            fma8u(a0, a1, q3, wh * ww);
        }
    }

    float4* o = (float4*)(out + (size_t)idx * 8);
    o[0] = a0;
    o[1] = a1;
}

// ---------- fallback (channel-first fp32 direct, known-correct) ----------
__global__ __launch_bounds__(256) void sample_cf(
    const float* __restrict__ xyz, const int* __restrict__ boundp,
    const float* __restrict__ Lg, const float* __restrict__ Hp,
    float* __restrict__ out, int N) {
    int n = blockIdx.x * blockDim.x + threadIdx.x;
    if (n >= N) return;
    float invb = 1.0f / (float)boundp[0];
    float x = xyz[(size_t)3 * n + 0] * invb;
    float y = xyz[(size_t)3 * n + 1] * invb;
    float z = xyz[(size_t)3 * n + 2] * invb;
    float acc[8];
#pragma unroll
    for (int c = 0; c < 8; ++c) acc[c] = 0.f;
    {
        int x0, x1, y0, y1, z0, z1;
        float wx, wy, wz;
        to_idx(x, LRES, x0, x1, wx);
        to_idx(y, LRES, y0, y1, wy);
        to_idx(z, LRES, z0, z1, wz);
        float ux = 1.f - wx, uy = 1.f - wy, uz = 1.f - wz;
        size_t i8[8];
        i8[0] = ((size_t)z0 * LRES + y0) * LRES + x0;
        i8[1] = ((size_t)z0 * LRES + y0) * LRES + x1;
        i8[2] = ((size_t)z0 * LRES + y1) * LRES + x0;
        i8[3] = ((size_t)z0 * LRES + y1) * LRES + x1;
        i8[4] = ((size_t)z1 * LRES + y0) * LRES + x0;
        i8[5] = ((size_t)z1 * LRES + y0) * LRES + x1;
        i8[6] = ((size_t)z1 * LRES + y1) * LRES + x0;
        i8[7] = ((size_t)z1 * LRES + y1) * LRES + x1;
        float w8[8] = {uz * uy * ux, uz * uy * wx, uz * wy * ux, uz * wy * wx,
                       wz * uy * ux, wz * uy * wx, wz * wy * ux, wz * wy * wx};
#pragma unroll
        for (int c = 0; c < 8; ++c) {
            const float* g = Lg + (size_t)c * LVOX;
            float s = 0.f;
#pragma unroll
            for (int k = 0; k < 8; ++k) s = fmaf(g[i8[k]], w8[k], s);
            acc[c] += s;
        }
    }
    {
        const float cw[3] = {x, y, z};
        const float ch[3] = {y, z, x};
        for (int p = 0; p < 3; ++p) {
            int w0, w1, h0, h1;
            float ww, wh;
            to_idx(cw[p], HRES, w0, w1, ww);
            to_idx(ch[p], HRES, h0, h1, wh);
            float uw = 1.f - ww, uh = 1.f - wh;
            size_t i4[4] = {(size_t)h0 * HRES + w0, (size_t)h0 * HRES + w1,
                            (size_t)h1 * HRES + w0, (size_t)h1 * HRES + w1};
            float w4[4] = {uh * uw, uh * ww, wh * uw, wh * ww};
            const float* pb = Hp + (size_t)p * 8 * PPIX;
#pragma unroll
            for (int c = 0; c < 8; ++c) {
                const float* g = pb + (size_t)c * PPIX;
                float s = 0.f;
#pragma unroll
                for (int k = 0; k < 4; ++k) s = fmaf(g[i4[k]], w4[k], s);
                acc[c] += s;
            }
        }
    }
#pragma unroll
    for (int c = 0; c < 8; ++c) out[(size_t)n * 8 + c] = acc[c];
}

extern "C" void kernel_launch(void* const* d_in, const int* in_sizes, int n_in,
                              void* d_out, int out_size, void* d_ws, size_t ws_size,
                              hipStream_t stream) {
    const float* xyz = (const float*)d_in[0];
    const int* bound = (const int*)d_in[1];
    const float* Lg = (const float*)d_in[2]; // [8,128,128,128]
    const float* Hp = (const float*)d_in[3]; // [3,8,1024,1024]
    float* out = (float*)d_out;
    int N = in_sizes[0] / 3;

    // workspace layout (bytes)
    size_t off = 0;
    size_t gclb_b = (size_t)LVOX * 16;          // 33,554,432
    size_t pclb_b = (size_t)3 * PPIX * 16;      // 50,331,648
    size_t sort_b = (size_t)N * 16;             // 32,000,000
    size_t hist_b = (size_t)NCELLS * 4;         // 1,048,576
    size_t bsum_b = (size_t)(NCELLS / 256) * 4; // 4096
    size_t need = gclb_b + pclb_b + sort_b + hist_b + bsum_b;

    if (ws_size >= need) {
        char* w = (char*)d_ws;
        uint4* gclb = (uint4*)(w + off);     off += gclb_b;
        uint4* pclb = (uint4*)(w + off);     off += pclb_b;
        float4* sorted = (float4*)(w + off); off += sort_b;
        unsigned* hist = (unsigned*)(w + off); off += hist_b;
        unsigned* bsum = (unsigned*)(w + off);

        transpose_bf<<<(LVOX + 255) / 256, 256, 0, stream>>>(Lg, gclb, LVOX);
        for (int p = 0; p < 3; ++p) {
            transpose_bf<<<(PPIX + 255) / 256, 256, 0, stream>>>(
                Hp + (size_t)p * 8 * PPIX, pclb + (size_t)p * PPIX, PPIX);
        }
        hipMemsetAsync(hist, 0, hist_b, stream);
        hist_k<<<(N + 255) / 256, 256, 0, stream>>>(xyz, bound, hist, N);
        scan1_k<<<NCELLS / 256, 256, 0, stream>>>(hist, bsum);
        scan2_k<<<1, 1024, 0, stream>>>(bsum, NCELLS / 256);
        for (int p = 0; p < SCAT_PASSES; ++p) {
            scatter_k<<<(N + 255) / 256, 256, 0, stream>>>(xyz, bound, hist, bsum,
                                                           sorted, N, p);
        }
        sample_srt<<<(N + 255) / 256, 256, 0, stream>>>(sorted, gclb, pclb, out, N);
    } else {
        sample_cf<<<(N + 255) / 256, 256, 0, stream>>>(xyz, bound, Lg, Hp, out, N);
    }
}

// Round 4
// 410.339 us; speedup vs baseline: 2.6919x; 1.2825x over previous
//
#include <hip/hip_runtime.h>

#define LRES 128
#define HRES 1024
#define CB 16                 // cells per axis
#define NC (CB * CB * CB)     // 4096 cells
#define NBSORT 256            // fixed block count for hist/scatter (must match)
#define BT 256                // threads per block

static const int LVOX = LRES * LRES * LRES; // 2,097,152
static const int PPIX = HRES * HRES;        // 1,048,576

// ---------- helpers ----------

// Replicates reference _to_idx exactly.
__device__ __forceinline__ void to_idx(float c, int size, int& i0, int& i1, float& w) {
    float p = (c + 1.0f) * 0.5f * (float)(size - 1);
    float f = floorf(p);
    w = p - f;
    int i = (int)f;
    i0 = min(max(i, 0), size - 1);
    i1 = min(i0 + 1, size - 1);
}

// float -> bf16 (RNE)
__device__ __forceinline__ unsigned f2bf(float f) {
    unsigned u = __float_as_uint(f);
    return (u + 0x7FFFu + ((u >> 16) & 1u)) >> 16;
}
__device__ __forceinline__ float bflo(unsigned u) { return __uint_as_float(u << 16); }
__device__ __forceinline__ float bfhi(unsigned u) { return __uint_as_float(u & 0xFFFF0000u); }

__device__ __forceinline__ void fma8u(float4& a0, float4& a1, uint4 q, float w) {
    a0.x = fmaf(bflo(q.x), w, a0.x);
    a0.y = fmaf(bfhi(q.x), w, a0.y);
    a0.z = fmaf(bflo(q.y), w, a0.z);
    a0.w = fmaf(bfhi(q.y), w, a0.w);
    a1.x = fmaf(bflo(q.z), w, a1.x);
    a1.y = fmaf(bfhi(q.z), w, a1.y);
    a1.z = fmaf(bflo(q.w), w, a1.z);
    a1.w = fmaf(bfhi(q.w), w, a1.w);
}

__device__ __forceinline__ unsigned spread3(unsigned x) {
    x &= 0x3FFu;
    x = (x | (x << 16)) & 0x030000FFu;
    x = (x | (x << 8)) & 0x0300F00Fu;
    x = (x | (x << 4)) & 0x030C30C3u;
    x = (x | (x << 2)) & 0x09249249u;
    return x;
}
// Morton cell id on a 16^3 lattice (12-bit key)
__device__ __forceinline__ unsigned cell16(float x, float y, float z) {
    int cx = min(max((int)(x * (float)CB), 0), CB - 1);
    int cy = min(max((int)(y * (float)CB), 0), CB - 1);
    int cz = min(max((int)(z * (float)CB), 0), CB - 1);
    return spread3(cx) | (spread3(cy) << 1) | (spread3(cz) << 2);
}

// ---------- table transpose to channels-last bf16 ----------
__global__ __launch_bounds__(256) void transpose_bf(const float* __restrict__ src,
                                                    uint4* __restrict__ dst, int V) {
    int v = blockIdx.x * blockDim.x + threadIdx.x;
    if (v >= V) return;
    unsigned h[8];
#pragma unroll
    for (int c = 0; c < 8; ++c) h[c] = f2bf(src[(size_t)c * V + v]);
    uint4 o;
    o.x = h[0] | (h[1] << 16);
    o.y = h[2] | (h[3] << 16);
    o.z = h[4] | (h[5] << 16);
    o.w = h[6] | (h[7] << 16);
    dst[v] = o;
}

// ---------- atomic-free counting sort ----------

// Per-block private histogram (LDS), written to histmat[block][NC]. No global atomics.
__global__ __launch_bounds__(BT) void hist_pb(const float* __restrict__ xyz,
                                              const int* __restrict__ boundp,
                                              unsigned* __restrict__ histmat, int N) {
    __shared__ unsigned h[NC];
    for (int i = threadIdx.x; i < NC; i += BT) h[i] = 0u;
    __syncthreads();
    float invb = 1.0f / (float)boundp[0];
    for (int n = blockIdx.x * BT + threadIdx.x; n < N; n += NBSORT * BT) {
        float x = xyz[(size_t)3 * n + 0] * invb;
        float y = xyz[(size_t)3 * n + 1] * invb;
        float z = xyz[(size_t)3 * n + 2] * invb;
        atomicAdd(&h[cell16(x, y, z)], 1u);
    }
    __syncthreads();
    unsigned* row = histmat + (size_t)blockIdx.x * NC;
    for (int i = threadIdx.x; i < NC; i += BT) row[i] = h[i];
}

// For each cell c: exclusive prefix across blocks (in place) + per-cell total.
// Thread c reads histmat[b][c] for b=0..NBSORT-1 (coalesced across the wave).
__global__ __launch_bounds__(256) void rowpref(unsigned* __restrict__ histmat,
                                               unsigned* __restrict__ total) {
    int c = blockIdx.x * 256 + threadIdx.x; // 0..NC-1
    unsigned run = 0;
    for (int b = 0; b < NBSORT; ++b) {
        unsigned v = histmat[(size_t)b * NC + c];
        histmat[(size_t)b * NC + c] = run;
        run += v;
    }
    total[c] = run;
}

// Exclusive scan of NC totals -> cellbase. One block, 1024 threads, 4 elems each.
__global__ __launch_bounds__(1024) void scan2_k(const unsigned* __restrict__ total,
                                                unsigned* __restrict__ cellbase) {
    __shared__ unsigned s[1024];
    int tid = threadIdx.x;
    unsigned v[4];
    unsigned sum = 0;
#pragma unroll
    for (int k = 0; k < 4; ++k) {
        v[k] = total[tid * 4 + k];
        sum += v[k];
    }
    s[tid] = sum;
    __syncthreads();
    for (int o = 1; o < 1024; o <<= 1) {
        unsigned t = (tid >= o) ? s[tid - o] : 0u;
        __syncthreads();
        s[tid] += t;
        __syncthreads();
    }
    unsigned base = s[tid] - sum; // exclusive
#pragma unroll
    for (int k = 0; k < 4; ++k) {
        cellbase[tid * 4 + k] = base;
        base += v[k];
    }
}

// Scatter: block b seeds LDS counters with cellbase[c] + histmat[b][c], then
// ranks its points via LDS atomics. Same-block same-cell points are contiguous.
__global__ __launch_bounds__(BT) void scatter_pb(const float* __restrict__ xyz,
                                                 const int* __restrict__ boundp,
                                                 const unsigned* __restrict__ histmat,
                                                 const unsigned* __restrict__ cellbase,
                                                 float4* __restrict__ sorted, int N) {
    __shared__ unsigned cnt[NC];
    const unsigned* row = histmat + (size_t)blockIdx.x * NC;
    for (int i = threadIdx.x; i < NC; i += BT) cnt[i] = cellbase[i] + row[i];
    __syncthreads();
    float invb = 1.0f / (float)boundp[0];
    for (int n = blockIdx.x * BT + threadIdx.x; n < N; n += NBSORT * BT) {
        float x = xyz[(size_t)3 * n + 0] * invb;
        float y = xyz[(size_t)3 * n + 1] * invb;
        float z = xyz[(size_t)3 * n + 2] * invb;
        unsigned c = cell16(x, y, z);
        unsigned d = atomicAdd(&cnt[c], 1u);
        sorted[d] = make_float4(x, y, z, __int_as_float(n));
    }
}

// ---------- main sampler (sorted order, bf16 channels-last tables) ----------
__global__ __launch_bounds__(256) void sample_srt(const float4* __restrict__ sorted,
                                                  const uint4* __restrict__ gclb,
                                                  const uint4* __restrict__ pclb,
                                                  float* __restrict__ out, int N) {
    int i = blockIdx.x * blockDim.x + threadIdx.x;
    if (i >= N) return;
    float4 rec = sorted[i];
    float x = rec.x, y = rec.y, z = rec.z;
    int idx = __float_as_int(rec.w);

    // --- grid indices + issue all 8 grid loads ---
    int x0, x1, y0, y1, z0, z1;
    float wx, wy, wz;
    to_idx(x, LRES, x0, x1, wx);
    to_idx(y, LRES, y0, y1, wy);
    to_idx(z, LRES, z0, z1, wz);
    const uint4* b00 = gclb + ((size_t)z0 * LRES + y0) * LRES;
    const uint4* b01 = gclb + ((size_t)z0 * LRES + y1) * LRES;
    const uint4* b10 = gclb + ((size_t)z1 * LRES + y0) * LRES;
    const uint4* b11 = gclb + ((size_t)z1 * LRES + y1) * LRES;
    uint4 g0 = b00[x0], g1 = b00[x1], g2 = b01[x0], g3 = b01[x1];
    uint4 g4 = b10[x0], g5 = b10[x1], g6 = b11[x0], g7 = b11[x1];

    // --- plane indices + issue all 12 plane loads ---
    const float cw[3] = {x, y, z};
    const float ch[3] = {y, z, x};
    float pww[3], pwh[3];
    uint4 r[12];
#pragma unroll
    for (int p = 0; p < 3; ++p) {
        int w0, w1, h0, h1;
        to_idx(cw[p], HRES, w0, w1, pww[p]);
        to_idx(ch[p], HRES, h0, h1, pwh[p]);
        const uint4* base = pclb + (size_t)p * PPIX;
        const uint4* r0 = base + (size_t)h0 * HRES;
        const uint4* r1 = base + (size_t)h1 * HRES;
        r[4 * p + 0] = r0[w0];
        r[4 * p + 1] = r0[w1];
        r[4 * p + 2] = r1[w0];
        r[4 * p + 3] = r1[w1];
    }

    // --- FMAs ---
    float4 a0 = make_float4(0.f, 0.f, 0.f, 0.f);
    float4 a1 = make_float4(0.f, 0.f, 0.f, 0.f);
    {
        float ux = 1.f - wx, uy = 1.f - wy, uz = 1.f - wz;
        fma8u(a0, a1, g0, uz * uy * ux);
        fma8u(a0, a1, g1, uz * uy * wx);
        fma8u(a0, a1, g2, uz * wy * ux);
        fma8u(a0, a1, g3, uz * wy * wx);
        fma8u(a0, a1, g4, wz * uy * ux);
        fma8u(a0, a1, g5, wz * uy * wx);
        fma8u(a0, a1, g6, wz * wy * ux);
        fma8u(a0, a1, g7, wz * wy * wx);
    }
#pragma unroll
    for (int p = 0; p < 3; ++p) {
        float ww = pww[p], wh = pwh[p];
        float uw = 1.f - ww, uh = 1.f - wh;
        fma8u(a0, a1, r[4 * p + 0], uh * uw);
        fma8u(a0, a1, r[4 * p + 1], uh * ww);
        fma8u(a0, a1, r[4 * p + 2], wh * uw);
        fma8u(a0, a1, r[4 * p + 3], wh * ww);
    }

    float4* o = (float4*)(out + (size_t)idx * 8);
    o[0] = a0;
    o[1] = a1;
}

// ---------- fallback (channel-first fp32 direct, known-correct) ----------
__global__ __launch_bounds__(256) void sample_cf(
    const float* __restrict__ xyz, const int* __restrict__ boundp,
    const float* __restrict__ Lg, const float* __restrict__ Hp,
    float* __restrict__ out, int N) {
    int n = blockIdx.x * blockDim.x + threadIdx.x;
    if (n >= N) return;
    float invb = 1.0f / (float)boundp[0];
    float x = xyz[(size_t)3 * n + 0] * invb;
    float y = xyz[(size_t)3 * n + 1] * invb;
    float z = xyz[(size_t)3 * n + 2] * invb;
    float acc[8];
#pragma unroll
    for (int c = 0; c < 8; ++c) acc[c] = 0.f;
    {
        int x0, x1, y0, y1, z0, z1;
        float wx, wy, wz;
        to_idx(x, LRES, x0, x1, wx);
        to_idx(y, LRES, y0, y1, wy);
        to_idx(z, LRES, z0, z1, wz);
        float ux = 1.f - wx, uy = 1.f - wy, uz = 1.f - wz;
        size_t i8[8];
        i8[0] = ((size_t)z0 * LRES + y0) * LRES + x0;
        i8[1] = ((size_t)z0 * LRES + y0) * LRES + x1;
        i8[2] = ((size_t)z0 * LRES + y1) * LRES + x0;
        i8[3] = ((size_t)z0 * LRES + y1) * LRES + x1;
        i8[4] = ((size_t)z1 * LRES + y0) * LRES + x0;
        i8[5] = ((size_t)z1 * LRES + y0) * LRES + x1;
        i8[6] = ((size_t)z1 * LRES + y1) * LRES + x0;
        i8[7] = ((size_t)z1 * LRES + y1) * LRES + x1;
        float w8[8] = {uz * uy * ux, uz * uy * wx, uz * wy * ux, uz * wy * wx,
                       wz * uy * ux, wz * uy * wx, wz * wy * ux, wz * wy * wx};
#pragma unroll
        for (int c = 0; c < 8; ++c) {
            const float* g = Lg + (size_t)c * LVOX;
            float s = 0.f;
#pragma unroll
            for (int k = 0; k < 8; ++k) s = fmaf(g[i8[k]], w8[k], s);
            acc[c] += s;
        }
    }
    {
        const float cw[3] = {x, y, z};
        const float ch[3] = {y, z, x};
        for (int p = 0; p < 3; ++p) {
            int w0, w1, h0, h1;
            float ww, wh;
            to_idx(cw[p], HRES, w0, w1, ww);
            to_idx(ch[p], HRES, h0, h1, wh);
            float uw = 1.f - ww, uh = 1.f - wh;
            size_t i4[4] = {(size_t)h0 * HRES + w0, (size_t)h0 * HRES + w1,
                            (size_t)h1 * HRES + w0, (size_t)h1 * HRES + w1};
            float w4[4] = {uh * uw, uh * ww, wh * uw, wh * ww};
            const float* pb = Hp + (size_t)p * 8 * PPIX;
#pragma unroll
            for (int c = 0; c < 8; ++c) {
                const float* g = pb + (size_t)c * PPIX;
                float s = 0.f;
#pragma unroll
                for (int k = 0; k < 4; ++k) s = fmaf(g[i4[k]], w4[k], s);
                acc[c] += s;
            }
        }
    }
#pragma unroll
    for (int c = 0; c < 8; ++c) out[(size_t)n * 8 + c] = acc[c];
}

extern "C" void kernel_launch(void* const* d_in, const int* in_sizes, int n_in,
                              void* d_out, int out_size, void* d_ws, size_t ws_size,
                              hipStream_t stream) {
    const float* xyz = (const float*)d_in[0];
    const int* bound = (const int*)d_in[1];
    const float* Lg = (const float*)d_in[2]; // [8,128,128,128]
    const float* Hp = (const float*)d_in[3]; // [3,8,1024,1024]
    float* out = (float*)d_out;
    int N = in_sizes[0] / 3;

    // workspace layout (bytes)
    size_t off = 0;
    size_t gclb_b = (size_t)LVOX * 16;            // 32 MiB
    size_t pclb_b = (size_t)3 * PPIX * 16;        // 48 MiB
    size_t sort_b = (size_t)N * 16;               // 32 MB
    size_t hmat_b = (size_t)NBSORT * NC * 4;      // 4 MiB
    size_t tot_b = (size_t)NC * 4;                // 16 KiB
    size_t cb_b = (size_t)NC * 4;                 // 16 KiB
    size_t need = gclb_b + pclb_b + sort_b + hmat_b + tot_b + cb_b;

    if (ws_size >= need) {
        char* w = (char*)d_ws;
        uint4* gclb = (uint4*)(w + off);        off += gclb_b;
        uint4* pclb = (uint4*)(w + off);        off += pclb_b;
        float4* sorted = (float4*)(w + off);    off += sort_b;
        unsigned* hmat = (unsigned*)(w + off);  off += hmat_b;
        unsigned* total = (unsigned*)(w + off); off += tot_b;
        unsigned* cbase = (unsigned*)(w + off);

        transpose_bf<<<(LVOX + 255) / 256, 256, 0, stream>>>(Lg, gclb, LVOX);
        for (int p = 0; p < 3; ++p) {
            transpose_bf<<<(PPIX + 255) / 256, 256, 0, stream>>>(
                Hp + (size_t)p * 8 * PPIX, pclb + (size_t)p * PPIX, PPIX);
        }
        hist_pb<<<NBSORT, BT, 0, stream>>>(xyz, bound, hmat, N);
        rowpref<<<NC / 256, 256, 0, stream>>>(hmat, total);
        scan2_k<<<1, 1024, 0, stream>>>(total, cbase);
        scatter_pb<<<NBSORT, BT, 0, stream>>>(xyz, bound, hmat, cbase, sorted, N);
        sample_srt<<<(N + 255) / 256, 256, 0, stream>>>(sorted, gclb, pclb, out, N);
    } else {
        sample_cf<<<(N + 255) / 256, 256, 0, stream>>>(xyz, bound, Lg, Hp, out, N);
    }
}